// Round 8
// baseline (167.171 us; speedup 1.0000x reference)
//
#include <hip/hip_runtime.h>
#include <math.h>

// Chamfer distance, B=8, N=M=8192, D=3, fp32.
// out = mean_m( min_n dist2 ) + mean_n( min_m dist2 )
//
// dist2 = |q|^2 + (|t|^2 - 2 q.t); quads (-2t, |t|^2) precomputed to global.
// R7: targets stream through the SCALAR pipe. R4/R5 post-mortem: ds_read_b128
// is return-bandwidth-bound (~12 cyc of the per-CU LDS pipe even for
// broadcasts), and per-CU LDS time (41-82us) matched the measured stalls.
// Wave-uniform quads belong in SGPRs: s_load writes 16 SGPRs once, not
// 64 lanes x 4 VGPRs. Inner loop: ping-pong 8-quad SGPR buffers loaded one
// batch ahead (2x s_load_dwordx16), Q=8 queries/thread in VGPRs.
// 232 VALU ops / 4096 pairs = 3.63 ops/pair -> ~50us VALU floor.
// No atomics (R2 lesson): partial mins via coalesced stores + merge/final.

#define B_      8
#define N_      8192
#define Q_      8            // queries per thread
#define S_      16           // target splits per pass
#define CHUNK_  (N_ / S_)    // 512 targets per chunk

// ws layout: quadX float4[BN] (1MB), quadY float4[BN] (1MB),
//            partX float[S_][BN] (4MB), partY float[S_][BN] (4MB), bsum[512]

__global__ void prep_kernel(const float* __restrict__ x, const float* __restrict__ y,
                            float4* __restrict__ quadX, float4* __restrict__ quadY,
                            int BN, int BM) {
    int i = blockIdx.x * blockDim.x + threadIdx.x;
    if (i >= BN + BM) return;
    const float* src;
    float4* dst;
    int k;
    if (i < BN) { src = x; dst = quadX; k = i; }
    else        { src = y; dst = quadY; k = i - BN; }
    float a0 = src[3 * k + 0];
    float a1 = src[3 * k + 1];
    float a2 = src[3 * k + 2];
    dst[k] = make_float4(-2.0f * a0, -2.0f * a1, -2.0f * a2,
                         fmaf(a0, a0, fmaf(a1, a1, a2 * a2)));
}

// grid (4, 8, 32): z<16 -> queries=x, targets=quadY; z>=16 -> queries=y, quadX.
__global__ __launch_bounds__(256)
void minpass_kernel(const float* __restrict__ x, const float* __restrict__ y,
                    const float4* __restrict__ quadX, const float4* __restrict__ quadY,
                    float* __restrict__ partX, float* __restrict__ partY) {
    const int b    = blockIdx.y;
    const int z    = blockIdx.z;       // 0..31
    const int pass = z >> 4;           // 0: q=x,t=y   1: q=y,t=x
    const int s    = z & (S_ - 1);

    const float*  qpts = pass ? y : x;
    const float4* tq   = pass ? quadX : quadY;
    float*        part = pass ? partY : partX;

    // ---- queries: 8 consecutive points = 96B -> 6 coalesced float4 loads ----
    const int iq0 = (blockIdx.x * blockDim.x + threadIdx.x) * Q_;
    const float4* qp4 = (const float4*)(qpts + ((long)b * N_ + iq0) * 3);
    float qx[Q_], qy[Q_], qz[Q_];
    {
        const float4 f0 = qp4[0], f1 = qp4[1], f2 = qp4[2];
        const float4 f3 = qp4[3], f4 = qp4[4], f5 = qp4[5];
        qx[0]=f0.x; qy[0]=f0.y; qz[0]=f0.z;
        qx[1]=f0.w; qy[1]=f1.x; qz[1]=f1.y;
        qx[2]=f1.z; qy[2]=f1.w; qz[2]=f2.x;
        qx[3]=f2.y; qy[3]=f2.z; qz[3]=f2.w;
        qx[4]=f3.x; qy[4]=f3.y; qz[4]=f3.z;
        qx[5]=f3.w; qy[5]=f4.x; qz[5]=f4.y;
        qx[6]=f4.z; qy[6]=f4.w; qz[6]=f5.x;
        qx[7]=f5.y; qy[7]=f5.z; qz[7]=f5.w;
    }

    // Wave-uniform target base: loads below compile to s_load (quads -> SGPRs).
    const float4* base = tq + (long)b * N_ + s * CHUNK_;

    float m[Q_];
#pragma unroll
    for (int i = 0; i < Q_; ++i) m[i] = __builtin_inff();

#define COMPUTE(T)                                                                     \
    {                                                                                  \
        _Pragma("unroll")                                                              \
        for (int i = 0; i < Q_; ++i) {                                                 \
            float s0 = fmaf(qx[i], T[0].x, fmaf(qy[i], T[0].y, fmaf(qz[i], T[0].z, T[0].w))); \
            float s1 = fmaf(qx[i], T[1].x, fmaf(qy[i], T[1].y, fmaf(qz[i], T[1].z, T[1].w))); \
            float s2 = fmaf(qx[i], T[2].x, fmaf(qy[i], T[2].y, fmaf(qz[i], T[2].z, T[2].w))); \
            float s3 = fmaf(qx[i], T[3].x, fmaf(qy[i], T[3].y, fmaf(qz[i], T[3].z, T[3].w))); \
            float s4 = fmaf(qx[i], T[4].x, fmaf(qy[i], T[4].y, fmaf(qz[i], T[4].z, T[4].w))); \
            float s5 = fmaf(qx[i], T[5].x, fmaf(qy[i], T[5].y, fmaf(qz[i], T[5].z, T[5].w))); \
            float s6 = fmaf(qx[i], T[6].x, fmaf(qy[i], T[6].y, fmaf(qz[i], T[6].z, T[6].w))); \
            float s7 = fmaf(qx[i], T[7].x, fmaf(qy[i], T[7].y, fmaf(qz[i], T[7].z, T[7].w))); \
            float u0 = fminf(fminf(s0, s1), s2);   /* v_min3 */                        \
            float u1 = fminf(fminf(s3, s4), s5);   /* v_min3 */                        \
            float u2 = fminf(fminf(s6, s7), u0);   /* v_min3 */                        \
            m[i]     = fminf(fminf(u1, u2), m[i]); /* v_min3 */                        \
        }                                                                              \
    }

    // Ping-pong two 8-quad uniform buffers; load one batch ahead so the
    // s_load latency hides under ~464 cycles of compute.
    float4 ta[8], tb[8];
#pragma unroll
    for (int k = 0; k < 8; ++k) ta[k] = base[k];

    for (int j = 0; j < CHUNK_; j += 16) {
#pragma unroll
        for (int k = 0; k < 8; ++k) tb[k] = base[j + 8 + k];
        COMPUTE(ta)
        // NOTE: last iteration prefetches 128B past this chunk — lands in the
        // following ws region (quads/parts), always allocated, never used.
#pragma unroll
        for (int k = 0; k < 8; ++k) ta[k] = base[j + 16 + k];
        COMPUTE(tb)
    }
#undef COMPUTE

    // ---- emit partial mins (two coalesced float4 stores) ----
    float r[Q_];
#pragma unroll
    for (int i = 0; i < Q_; ++i) {
        float xn = fmaf(qx[i], qx[i], fmaf(qy[i], qy[i], qz[i] * qz[i]));
        r[i] = fmaxf(m[i] + xn, 0.0f);   // clamp cancellation; dist2 >= 0
    }
    float* dst = part + (long)s * (B_ * N_) + (long)b * N_ + iq0;
    *(float4*)(dst + 0) = make_float4(r[0], r[1], r[2], r[3]);
    *(float4*)(dst + 4) = make_float4(r[4], r[5], r[6], r[7]);
}

// One thread per query slot: min over S_ partials, then deterministic block sum.
__global__ __launch_bounds__(256)
void merge_kernel(const float* __restrict__ partX, const float* __restrict__ partY,
                  float* __restrict__ bsum, int BN) {
    const int g = blockIdx.x * blockDim.x + threadIdx.x;
    const float* base = (g < BN) ? (partX + g) : (partY + (g - BN));

    float m = __builtin_inff();
#pragma unroll
    for (int s = 0; s < S_; ++s)
        m = fminf(m, base[(long)s * BN]);

    for (int off = 32; off > 0; off >>= 1)
        m += __shfl_down(m, off, 64);
    __shared__ float wsum[4];
    const int lane = threadIdx.x & 63;
    const int w    = threadIdx.x >> 6;
    if (lane == 0) wsum[w] = m;
    __syncthreads();
    if (threadIdx.x == 0)
        bsum[blockIdx.x] = (wsum[0] + wsum[1]) + (wsum[2] + wsum[3]);
}

// Single wave: deterministic sum of block partials, scaled.
__global__ __launch_bounds__(64)
void final_kernel(const float* __restrict__ bsum, float* __restrict__ out,
                  int nb, float scale) {
    float s = 0.0f;
    for (int k = threadIdx.x; k < nb; k += 64)
        s += bsum[k];
    for (int off = 32; off > 0; off >>= 1)
        s += __shfl_down(s, off, 64);
    if (threadIdx.x == 0) out[0] = s * scale;
}

extern "C" void kernel_launch(void* const* d_in, const int* in_sizes, int n_in,
                              void* d_out, int out_size, void* d_ws, size_t ws_size,
                              hipStream_t stream) {
    const float* x = (const float*)d_in[0];  // [8, 8192, 3]
    const float* y = (const float*)d_in[1];  // [8, 8192, 3]
    float* out = (float*)d_out;

    const int BN = B_ * N_;

    float4* quadX = (float4*)d_ws;
    float4* quadY = quadX + BN;
    float*  partX = (float*)(quadY + BN);
    float*  partY = partX + (size_t)S_ * BN;
    float*  bsum  = partY + (size_t)S_ * BN;

    prep_kernel<<<(2 * BN + 255) / 256, 256, 0, stream>>>(x, y, quadX, quadY, BN, BN);

    // fused both-direction minpass: grid (4, 8, 32) = 1024 blocks
    minpass_kernel<<<dim3(N_ / (256 * Q_), B_, 2 * S_), 256, 0, stream>>>(
        x, y, quadX, quadY, partX, partY);

    const int nb = 2 * BN / 256;  // 512
    merge_kernel<<<nb, 256, 0, stream>>>(partX, partY, bsum, BN);
    final_kernel<<<1, 64, 0, stream>>>(bsum, out, nb, 1.0f / 65536.0f);
}

// Round 9
// 139.456 us; speedup vs baseline: 1.1987x; 1.1987x over previous
//
#include <hip/hip_runtime.h>
#include <math.h>

// Chamfer distance, B=8, N=M=8192, D=3, fp32.
// out = mean_m( min_n dist2 ) + mean_n( min_m dist2 )
//
// dist2 = |q|^2 + (|t|^2 - 2 q.t); block stages its chunk's target quads
// (-2t, |t|^2) into LDS; inner loop = uniform-address ds_read_b128 broadcast.
// R8 (from R5/R7 post-mortems):
//  - SMEM streaming (R7) serializes: SMEM returns out-of-order, lgkmcnt(0)
//    drains the prefetch too. LDS ds_read is in-order countable -> ping-pong
//    prefetch DOES pipeline. Back to LDS, with explicit t[4] ping-pong
//    (16 VGPRs -- a batch the compiler will actually keep in registers;
//    R5's t[8]=32 regs got collapsed, VGPR_Count=40 proved it).
//  - S=32 -> 2048 blocks = 8 blocks/CU = 8 waves/SIMD (R5 ran at 4).
//  - no atomics (R2 lesson); partial mins via coalesced stores + merge/final.
// Model: VALU floor 48us/SIMD (3.5 ops/pair), LDS pipe 41us/CU, overlapped.
// ws usage: 2*S_*BN*4 = 16.8 MB parts + bsum.

#define B_      8
#define N_      8192
#define Q_      8            // queries per thread
#define S_      32           // target splits per pass
#define CHUNK_  (N_ / S_)    // 256 targets per block

__global__ __launch_bounds__(256)
void minpass_kernel(const float* __restrict__ x, const float* __restrict__ y,
                    float* __restrict__ partX, float* __restrict__ partY) {
    __shared__ float4 sq[CHUNK_ + 8];   // +8: ping-pong prefetch overshoot pad

    const int b    = blockIdx.y;
    const int z    = blockIdx.z;       // 0..63
    const int pass = z >> 5;           // 0: q=x,t=y   1: q=y,t=x
    const int s    = z & (S_ - 1);

    const float* qpts = pass ? y : x;
    const float* tpts = pass ? x : y;
    float*       part = pass ? partY : partX;

    // ---- stage: 256 target quads, one per thread ----
    {
        const float* p = tpts + ((long)b * N_ + s * CHUNK_ + threadIdx.x) * 3;
        float a0 = p[0], a1 = p[1], a2 = p[2];
        sq[threadIdx.x] = make_float4(-2.0f * a0, -2.0f * a1, -2.0f * a2,
                                      fmaf(a0, a0, fmaf(a1, a1, a2 * a2)));
    }
    __syncthreads();

    // ---- queries: 8 consecutive points = 96B -> 6 coalesced float4 loads ----
    const int iq0 = (blockIdx.x * blockDim.x + threadIdx.x) * Q_;
    const float4* qp4 = (const float4*)(qpts + ((long)b * N_ + iq0) * 3);
    float qx[Q_], qy[Q_], qz[Q_];
    {
        const float4 f0 = qp4[0], f1 = qp4[1], f2 = qp4[2];
        const float4 f3 = qp4[3], f4 = qp4[4], f5 = qp4[5];
        qx[0]=f0.x; qy[0]=f0.y; qz[0]=f0.z;
        qx[1]=f0.w; qy[1]=f1.x; qz[1]=f1.y;
        qx[2]=f1.z; qy[2]=f1.w; qz[2]=f2.x;
        qx[3]=f2.y; qy[3]=f2.z; qz[3]=f2.w;
        qx[4]=f3.x; qy[4]=f3.y; qz[4]=f3.z;
        qx[5]=f3.w; qy[5]=f4.x; qz[5]=f4.y;
        qx[6]=f4.z; qy[6]=f4.w; qz[6]=f5.x;
        qx[7]=f5.y; qy[7]=f5.z; qz[7]=f5.w;
    }

    float m[Q_];
#pragma unroll
    for (int i = 0; i < Q_; ++i) m[i] = __builtin_inff();

    // per query per 4 targets: 12 fma + 2 min3 = 14 ops / 4 pairs = 3.5/pair
#define COMPUTE(T)                                                                     \
    {                                                                                  \
        _Pragma("unroll")                                                              \
        for (int i = 0; i < Q_; ++i) {                                                 \
            float s0 = fmaf(qx[i], T[0].x, fmaf(qy[i], T[0].y, fmaf(qz[i], T[0].z, T[0].w))); \
            float s1 = fmaf(qx[i], T[1].x, fmaf(qy[i], T[1].y, fmaf(qz[i], T[1].z, T[1].w))); \
            float s2 = fmaf(qx[i], T[2].x, fmaf(qy[i], T[2].y, fmaf(qz[i], T[2].z, T[2].w))); \
            float s3 = fmaf(qx[i], T[3].x, fmaf(qy[i], T[3].y, fmaf(qz[i], T[3].z, T[3].w))); \
            float u0 = fminf(fminf(s0, s1), s2);        /* v_min3 */                   \
            m[i]     = fminf(fminf(s3, u0), m[i]);      /* v_min3 */                   \
        }                                                                              \
    }

    // ---- scan: explicit 4-target ping-pong; DS waits are in-order, so the
    // prefetched batch stays outstanding during COMPUTE (lgkmcnt(4)).
    float4 ta[4], tb[4];
#pragma unroll
    for (int k = 0; k < 4; ++k) ta[k] = sq[k];

    for (int j = 0; j < CHUNK_; j += 8) {
#pragma unroll
        for (int k = 0; k < 4; ++k) tb[k] = sq[j + 4 + k];
        COMPUTE(ta)
        // last iteration prefetches sq[CHUNK_..CHUNK_+3] -> pad, never used
#pragma unroll
        for (int k = 0; k < 4; ++k) ta[k] = sq[j + 8 + k];
        COMPUTE(tb)
    }
#undef COMPUTE

    // ---- emit partial mins (two coalesced float4 stores) ----
    float r[Q_];
#pragma unroll
    for (int i = 0; i < Q_; ++i) {
        float xn = fmaf(qx[i], qx[i], fmaf(qy[i], qy[i], qz[i] * qz[i]));
        r[i] = fmaxf(m[i] + xn, 0.0f);   // clamp cancellation; dist2 >= 0
    }
    float* dst = part + (long)s * (B_ * N_) + (long)b * N_ + iq0;
    *(float4*)(dst + 0) = make_float4(r[0], r[1], r[2], r[3]);
    *(float4*)(dst + 4) = make_float4(r[4], r[5], r[6], r[7]);
}

// One thread per query slot: min over S_ partials, then deterministic block sum.
__global__ __launch_bounds__(256)
void merge_kernel(const float* __restrict__ partX, const float* __restrict__ partY,
                  float* __restrict__ bsum, int BN) {
    const int g = blockIdx.x * blockDim.x + threadIdx.x;
    const float* base = (g < BN) ? (partX + g) : (partY + (g - BN));

    float m = __builtin_inff();
#pragma unroll
    for (int s = 0; s < S_; ++s)
        m = fminf(m, base[(long)s * BN]);

    for (int off = 32; off > 0; off >>= 1)
        m += __shfl_down(m, off, 64);
    __shared__ float wsum[4];
    const int lane = threadIdx.x & 63;
    const int w    = threadIdx.x >> 6;
    if (lane == 0) wsum[w] = m;
    __syncthreads();
    if (threadIdx.x == 0)
        bsum[blockIdx.x] = (wsum[0] + wsum[1]) + (wsum[2] + wsum[3]);
}

// Single wave: deterministic sum of block partials, scaled.
__global__ __launch_bounds__(64)
void final_kernel(const float* __restrict__ bsum, float* __restrict__ out,
                  int nb, float scale) {
    float s = 0.0f;
    for (int k = threadIdx.x; k < nb; k += 64)
        s += bsum[k];
    for (int off = 32; off > 0; off >>= 1)
        s += __shfl_down(s, off, 64);
    if (threadIdx.x == 0) out[0] = s * scale;
}

extern "C" void kernel_launch(void* const* d_in, const int* in_sizes, int n_in,
                              void* d_out, int out_size, void* d_ws, size_t ws_size,
                              hipStream_t stream) {
    const float* x = (const float*)d_in[0];  // [8, 8192, 3]
    const float* y = (const float*)d_in[1];  // [8, 8192, 3]
    float* out = (float*)d_out;

    const int BN = B_ * N_;

    float* partX = (float*)d_ws;                 // S_*BN floats = 8.4 MB
    float* partY = partX + (size_t)S_ * BN;      // 8.4 MB
    float* bsum  = partY + (size_t)S_ * BN;

    // fused both-direction minpass: grid (4, 8, 64) = 2048 blocks = 8/CU
    minpass_kernel<<<dim3(N_ / (256 * Q_), B_, 2 * S_), 256, 0, stream>>>(
        x, y, partX, partY);

    const int nb = 2 * BN / 256;  // 512
    merge_kernel<<<nb, 256, 0, stream>>>(partX, partY, bsum, BN);
    final_kernel<<<1, 64, 0, stream>>>(bsum, out, nb, 1.0f / 65536.0f);
}